// Round 2
// baseline (2181.363 us; speedup 1.0000x reference)
//
#include <hip/hip_runtime.h>
#include <hip/hip_bf16.h>
#include <stdint.h>

#define TOKENS 8192
#define DIN    4096
#define DOUT   16384

#define BM 256
#define BN 256
#define BK 32
#define NT (DIN / BK)   // 128 K-tiles

typedef short s16x8 __attribute__((ext_vector_type(8)));
typedef float f32x4 __attribute__((ext_vector_type(4)));

#define VMCNT(n) asm volatile("s_waitcnt vmcnt(" #n ")" ::: "memory")
#define BARRIER() do { asm volatile("" ::: "memory"); __builtin_amdgcn_s_barrier(); asm volatile("" ::: "memory"); } while (0)

__device__ __forceinline__ unsigned short f2bf(float f) {
  unsigned int u = __float_as_uint(f);
  u += 0x7fffu + ((u >> 16) & 1u);   // round-to-nearest-even
  return (unsigned short)(u >> 16);
}

// -------- Kernel 1: LayerNorm (no affine) fp32 -> bf16 bits, one block per row
__global__ __launch_bounds__(256) void ln_kernel(const float* __restrict__ x,
                                                 unsigned short* __restrict__ xn) {
  const int row = blockIdx.x;
  const float4* xr = reinterpret_cast<const float4*>(x + (size_t)row * DIN);
  float4 v[4];
  float sum = 0.f, ssq = 0.f;
#pragma unroll
  for (int i = 0; i < 4; ++i) {
    v[i] = xr[threadIdx.x + i * 256];
    sum += v[i].x + v[i].y + v[i].z + v[i].w;
    ssq += v[i].x * v[i].x + v[i].y * v[i].y + v[i].z * v[i].z + v[i].w * v[i].w;
  }
#pragma unroll
  for (int off = 32; off > 0; off >>= 1) {
    sum += __shfl_xor(sum, off, 64);
    ssq += __shfl_xor(ssq, off, 64);
  }
  __shared__ float red[8];
  const int wid = threadIdx.x >> 6;
  if ((threadIdx.x & 63) == 0) { red[wid] = sum; red[wid + 4] = ssq; }
  __syncthreads();
  sum = red[0] + red[1] + red[2] + red[3];
  ssq = red[4] + red[5] + red[6] + red[7];
  const float mean = sum * (1.f / DIN);
  const float var  = ssq * (1.f / DIN) - mean * mean;  // biased, as torch LN
  const float rs   = rsqrtf(var + 1e-5f);
  ushort4* xo = reinterpret_cast<ushort4*>(xn + (size_t)row * DIN);
#pragma unroll
  for (int i = 0; i < 4; ++i) {
    ushort4 o;
    o.x = f2bf((v[i].x - mean) * rs);
    o.y = f2bf((v[i].y - mean) * rs);
    o.z = f2bf((v[i].z - mean) * rs);
    o.w = f2bf((v[i].w - mean) * rs);
    xo[threadIdx.x + i * 256] = o;
  }
}

// -------- Kernel 2: W fp32 -> bf16 bits
__global__ __launch_bounds__(256) void cvt_kernel(const float* __restrict__ W,
                                                  unsigned short* __restrict__ Wb) {
  const size_t i = (size_t)blockIdx.x * 256 + threadIdx.x;
  float4 v = reinterpret_cast<const float4*>(W)[i];
  ushort4 o;
  o.x = f2bf(v.x); o.y = f2bf(v.y); o.z = f2bf(v.z); o.w = f2bf(v.w);
  reinterpret_cast<ushort4*>(Wb)[i] = o;
}

// -------- Kernel 3: C = sigmoid(A @ B^T)
// 256x256 tile, BK=32, 8 waves (2x4), 4-deep LDS ring, counted vmcnt(8),
// phase-split (2 phases/K-tile, 16 MFMA each), setprio, XOR bank swizzle
// applied as: linear LDS dest + inverse-swizzled GLOBAL source + swizzled ds_read.
__global__ __launch_bounds__(512, 2) void gemm_sig(const unsigned short* __restrict__ A,
                                                   const unsigned short* __restrict__ B,
                                                   float* __restrict__ C) {
  __shared__ unsigned short Asl[4][BM * BK];  // 64 KB (4 ring slots)
  __shared__ unsigned short Bsl[4][BN * BK];  // 64 KB

  // XCD-aware bijective swizzle (nwg = 2048, divisible by 8)
  const int bid = blockIdx.x;
  const int cpx = gridDim.x >> 3;
  const int swz = (bid & 7) * cpx + (bid >> 3);
  const int bm = swz & 31;      // TOKENS/BM = 32
  const int bn = swz >> 5;      // DOUT/BN  = 64

  const int tid  = threadIdx.x;
  const int wid  = tid >> 6;
  const int lane = tid & 63;
  const int wr = wid >> 2;      // 0..1 -> 128 output rows
  const int wc = wid & 3;       // 0..3 -> 64 output cols

  const unsigned short* gA = A + (size_t)bm * BM * DIN;
  const unsigned short* gB = B + (size_t)bn * BN * DIN;

  // Staging precompute. Instruction i (0,1) : lane covers LDS 16B-chunk
  // idx = i*512 + tid -> (row = idx>>2, lds slot s = idx&3). To land the
  // swizzled layout through the LINEAR global_load_lds write, the lane
  // fetches global 16B-slot c = s ^ ((row>>1)&3)  (XOR is an involution).
  const unsigned short* sAp[2];
  const unsigned short* sBp[2];
  int ldsOfs[2];
#pragma unroll
  for (int i = 0; i < 2; ++i) {
    const int chunk = i * 512 + tid;
    const int row = chunk >> 2;
    const int c = (chunk & 3) ^ ((row >> 1) & 3);
    sAp[i] = gA + (size_t)row * DIN + c * 8;
    sBp[i] = gB + (size_t)row * DIN + c * 8;
    ldsOfs[i] = i * 4096 + wid * 512;   // ushort units; wave-uniform base
  }

#define STAGE_A(tt, i) __builtin_amdgcn_global_load_lds( \
    (const __attribute__((address_space(1))) void*)(sAp[i] + (size_t)(tt) * BK), \
    (__attribute__((address_space(3))) void*)(&Asl[(tt) & 3][ldsOfs[i]]), 16, 0, 0)
#define STAGE_B(tt, i) __builtin_amdgcn_global_load_lds( \
    (const __attribute__((address_space(1))) void*)(sBp[i] + (size_t)(tt) * BK), \
    (__attribute__((address_space(3))) void*)(&Bsl[(tt) & 3][ldsOfs[i]]), 16, 0, 0)

  // Fragment ds_read offsets (ushort units), same XOR on the read side.
  int aofs[8], bofs[4];
#pragma unroll
  for (int m = 0; m < 8; ++m) {
    const int row = wr * 128 + m * 16 + (lane & 15);
    aofs[m] = row * BK + ((((lane >> 4) ^ ((row >> 1) & 3))) << 3);
  }
#pragma unroll
  for (int n = 0; n < 4; ++n) {
    const int row = wc * 64 + n * 16 + (lane & 15);
    bofs[n] = row * BK + ((((lane >> 4) ^ ((row >> 1) & 3))) << 3);
  }

  f32x4 acc[8][4] = {};

  // Prologue: stage tiles 0..2 (12 loads); tile 0 landed when <=8 outstanding.
  for (int tt = 0; tt < 3; ++tt) {
    STAGE_A(tt, 0); STAGE_A(tt, 1); STAGE_B(tt, 0); STAGE_B(tt, 1);
  }
  VMCNT(8);
  BARRIER();

  for (int t = 0; t < NT; ++t) {
    const unsigned short* Ab = &Asl[t & 3][0];
    const unsigned short* Bb = &Bsl[t & 3][0];
    const int tp = t + 3;       // stage 3 tiles ahead into slot freed at t-1

    // ---- phase 0: stage A(t+3) | read all A frags + B n0..1 | 16 MFMA
    if (tp < NT) { STAGE_A(tp, 0); STAGE_A(tp, 1); }
    s16x8 af[8];
#pragma unroll
    for (int m = 0; m < 8; ++m) af[m] = *reinterpret_cast<const s16x8*>(Ab + aofs[m]);
    s16x8 bf0 = *reinterpret_cast<const s16x8*>(Bb + bofs[0]);
    s16x8 bf1 = *reinterpret_cast<const s16x8*>(Bb + bofs[1]);
    BARRIER();
    __builtin_amdgcn_s_setprio(1);
#pragma unroll
    for (int m = 0; m < 8; ++m) {
      acc[m][0] = __builtin_amdgcn_mfma_f32_16x16x32_bf16(af[m], bf0, acc[m][0], 0, 0, 0);
      acc[m][1] = __builtin_amdgcn_mfma_f32_16x16x32_bf16(af[m], bf1, acc[m][1], 0, 0, 0);
    }
    __builtin_amdgcn_s_setprio(0);
    __builtin_amdgcn_sched_barrier(0);
    BARRIER();

    // ---- phase 1: stage B(t+3) | read B n2..3 | 16 MFMA | counted vmcnt
    if (tp < NT) { STAGE_B(tp, 0); STAGE_B(tp, 1); }
    s16x8 bf2 = *reinterpret_cast<const s16x8*>(Bb + bofs[2]);
    s16x8 bf3 = *reinterpret_cast<const s16x8*>(Bb + bofs[3]);
    BARRIER();
    __builtin_amdgcn_s_setprio(1);
#pragma unroll
    for (int m = 0; m < 8; ++m) {
      acc[m][2] = __builtin_amdgcn_mfma_f32_16x16x32_bf16(af[m], bf2, acc[m][2], 0, 0, 0);
      acc[m][3] = __builtin_amdgcn_mfma_f32_16x16x32_bf16(af[m], bf3, acc[m][3], 0, 0, 0);
    }
    __builtin_amdgcn_s_setprio(0);
    __builtin_amdgcn_sched_barrier(0);
    // tile t+1 must be landed: only tiles t+2,t+3 (8 loads) may stay in flight
    if (t < NT - 3)       { VMCNT(8); }
    else if (t == NT - 3) { VMCNT(4); }
    else                  { VMCNT(0); }
    BARRIER();
  }

#undef STAGE_A
#undef STAGE_B

  // Epilogue: C/D layout col = lane&15, row = (lane>>4)*4 + j
  const int crow0 = bm * BM + wr * 128 + (lane >> 4) * 4;
  const int ccol0 = bn * BN + wc * 64 + (lane & 15);
#pragma unroll
  for (int m = 0; m < 8; ++m)
#pragma unroll
    for (int n = 0; n < 4; ++n)
#pragma unroll
      for (int j = 0; j < 4; ++j) {
        const float v = acc[m][n][j];
        C[(size_t)(crow0 + m * 16 + j) * DOUT + (ccol0 + n * 16)] = 1.f / (1.f + __expf(-v));
      }
}

extern "C" void kernel_launch(void* const* d_in, const int* in_sizes, int n_in,
                              void* d_out, int out_size, void* d_ws, size_t ws_size,
                              hipStream_t stream) {
  const float* x = (const float*)d_in[0];
  const float* W = (const float*)d_in[1];
  float* out = (float*)d_out;

  // workspace: xn bf16 [8192,4096] (64 MiB) | Wb bf16 [16384,4096] (128 MiB)
  unsigned short* xn = (unsigned short*)d_ws;
  unsigned short* Wb = xn + (size_t)TOKENS * DIN;

  ln_kernel<<<TOKENS, 256, 0, stream>>>(x, xn);
  cvt_kernel<<<((size_t)DOUT * DIN) / 1024, 256, 0, stream>>>(W, Wb);
  gemm_sig<<<(TOKENS / BM) * (DOUT / BN), 512, 0, stream>>>(xn, Wb, out);
}

// Round 3
// 1750.397 us; speedup vs baseline: 1.2462x; 1.2462x over previous
//
#include <hip/hip_runtime.h>
#include <hip/hip_bf16.h>
#include <stdint.h>

#define TOKENS 8192
#define DIN    4096
#define DOUT   16384

#define BM 256
#define BN 256
#define BK 32
#define NT (DIN / BK)   // 128 K-tiles

typedef short s16x8 __attribute__((ext_vector_type(8)));
typedef float f32x4 __attribute__((ext_vector_type(4)));

#define VMCNT(n) asm volatile("s_waitcnt vmcnt(" #n ")" ::: "memory")
#define LGKMCNT0() asm volatile("s_waitcnt lgkmcnt(0)" ::: "memory")
#define BARRIER() __builtin_amdgcn_s_barrier()

__device__ __forceinline__ unsigned short f2bf(float f) {
  unsigned int u = __float_as_uint(f);
  u += 0x7fffu + ((u >> 16) & 1u);   // round-to-nearest-even
  return (unsigned short)(u >> 16);
}

// -------- Kernel 1: LayerNorm (no affine) fp32 -> bf16 bits, one block per row
__global__ __launch_bounds__(256) void ln_kernel(const float* __restrict__ x,
                                                 unsigned short* __restrict__ xn) {
  const int row = blockIdx.x;
  const float4* xr = reinterpret_cast<const float4*>(x + (size_t)row * DIN);
  float4 v[4];
  float sum = 0.f, ssq = 0.f;
#pragma unroll
  for (int i = 0; i < 4; ++i) {
    v[i] = xr[threadIdx.x + i * 256];
    sum += v[i].x + v[i].y + v[i].z + v[i].w;
    ssq += v[i].x * v[i].x + v[i].y * v[i].y + v[i].z * v[i].z + v[i].w * v[i].w;
  }
#pragma unroll
  for (int off = 32; off > 0; off >>= 1) {
    sum += __shfl_xor(sum, off, 64);
    ssq += __shfl_xor(ssq, off, 64);
  }
  __shared__ float red[8];
  const int wid = threadIdx.x >> 6;
  if ((threadIdx.x & 63) == 0) { red[wid] = sum; red[wid + 4] = ssq; }
  __syncthreads();
  sum = red[0] + red[1] + red[2] + red[3];
  ssq = red[4] + red[5] + red[6] + red[7];
  const float mean = sum * (1.f / DIN);
  const float var  = ssq * (1.f / DIN) - mean * mean;  // biased, as torch LN
  const float rs   = rsqrtf(var + 1e-5f);
  ushort4* xo = reinterpret_cast<ushort4*>(xn + (size_t)row * DIN);
#pragma unroll
  for (int i = 0; i < 4; ++i) {
    ushort4 o;
    o.x = f2bf((v[i].x - mean) * rs);
    o.y = f2bf((v[i].y - mean) * rs);
    o.z = f2bf((v[i].z - mean) * rs);
    o.w = f2bf((v[i].w - mean) * rs);
    xo[threadIdx.x + i * 256] = o;
  }
}

// -------- Kernel 2: W fp32 -> bf16 bits
__global__ __launch_bounds__(256) void cvt_kernel(const float* __restrict__ W,
                                                  unsigned short* __restrict__ Wb) {
  const size_t i = (size_t)blockIdx.x * 256 + threadIdx.x;
  float4 v = reinterpret_cast<const float4*>(W)[i];
  ushort4 o;
  o.x = f2bf(v.x); o.y = f2bf(v.y); o.z = f2bf(v.z); o.w = f2bf(v.w);
  reinterpret_cast<ushort4*>(Wb)[i] = o;
}

// -------- Kernel 3: C = sigmoid(A @ B^T)
// 256x256 tile, BK=32, 8 waves (2x4), 4-slot LDS ring, depth-3 prefetch,
// counted vmcnt(8), ONE barrier per K-tile, 32 contiguous MFMAs between
// barriers (compiler interleaves ds_read/MFMA with fine lgkmcnt).
// Bank-conflict-free via involution swizzle: linear LDS dest +
// inverse-swizzled GLOBAL source + same XOR on ds_read (R2-validated).
__global__ __launch_bounds__(512) void gemm_sig(const unsigned short* __restrict__ A,
                                                const unsigned short* __restrict__ B,
                                                float* __restrict__ C) {
  __shared__ unsigned short Asl[4 * BM * BK];  // 64 KB (4 ring slots)
  __shared__ unsigned short Bsl[4 * BN * BK];  // 64 KB

  // XCD-aware bijective swizzle (nwg = 2048, divisible by 8)
  const int bid = blockIdx.x;
  const int cpx = gridDim.x >> 3;
  const int swz = (bid & 7) * cpx + (bid >> 3);
  const int bm = swz & 31;      // TOKENS/BM = 32
  const int bn = swz >> 5;      // DOUT/BN  = 64

  const int tid  = threadIdx.x;
  const int wid  = tid >> 6;
  const int lane = tid & 63;
  const int wr = wid >> 2;      // 0..1 -> 128 output rows
  const int wc = wid & 3;       // 0..3 -> 64 output cols

  const unsigned short* gA = A + (size_t)bm * BM * DIN;
  const unsigned short* gB = B + (size_t)bn * BN * DIN;

  // Staging: instruction i (0,1) covers 16B-chunk idx = i*512+tid ->
  // (row = idx>>2, lds 16B-slot s = idx&3). Linear LDS dest; lane fetches
  // global 16B-slot c = s ^ ((row>>1)&3) so the READ-side XOR sees
  // swizzled data (involution).
  const unsigned short* sAp[2];
  const unsigned short* sBp[2];
  int ldsOfs[2];
#pragma unroll
  for (int i = 0; i < 2; ++i) {
    const int chunk = i * 512 + tid;
    const int row = chunk >> 2;
    const int c = (chunk & 3) ^ ((row >> 1) & 3);
    sAp[i] = gA + (size_t)row * DIN + c * 8;
    sBp[i] = gB + (size_t)row * DIN + c * 8;
    ldsOfs[i] = i * 4096 + wid * 512;   // ushort units; wave-uniform base
  }

#define STAGE_A(tt, i) __builtin_amdgcn_global_load_lds( \
    (const __attribute__((address_space(1))) void*)(sAp[i] + (size_t)(tt) * BK), \
    (__attribute__((address_space(3))) void*)(Asl + ((tt) & 3) * (BM * BK) + ldsOfs[i]), 16, 0, 0)
#define STAGE_B(tt, i) __builtin_amdgcn_global_load_lds( \
    (const __attribute__((address_space(1))) void*)(sBp[i] + (size_t)(tt) * BK), \
    (__attribute__((address_space(3))) void*)(Bsl + ((tt) & 3) * (BN * BK) + ldsOfs[i]), 16, 0, 0)

  // Fragment ds_read offsets (ushort units), same XOR on the read side.
  int aofs[8], bofs[4];
#pragma unroll
  for (int m = 0; m < 8; ++m) {
    const int row = wr * 128 + m * 16 + (lane & 15);
    aofs[m] = row * BK + (((lane >> 4) ^ ((row >> 1) & 3)) << 3);
  }
#pragma unroll
  for (int n = 0; n < 4; ++n) {
    const int row = wc * 64 + n * 16 + (lane & 15);
    bofs[n] = row * BK + (((lane >> 4) ^ ((row >> 1) & 3)) << 3);
  }

  f32x4 acc[8][4] = {};

  // Prologue: stage tiles 0..2 (12 loads); tile 0 landed when <=8 outstanding.
  for (int tt = 0; tt < 3; ++tt) {
    STAGE_A(tt, 0); STAGE_A(tt, 1); STAGE_B(tt, 0); STAGE_B(tt, 1);
  }
  VMCNT(8);
  BARRIER();

  for (int t = 0; t < NT; ++t) {
    const int tp = t + 3;       // stage 3 tiles ahead into slot freed at t-1
    if (tp < NT) { STAGE_A(tp, 0); STAGE_A(tp, 1); STAGE_B(tp, 0); STAGE_B(tp, 1); }

    const unsigned short* Ab = Asl + (t & 3) * (BM * BK);
    const unsigned short* Bb = Bsl + (t & 3) * (BN * BK);
    s16x8 af[8], bf[4];
#pragma unroll
    for (int m = 0; m < 8; ++m) af[m] = *reinterpret_cast<const s16x8*>(Ab + aofs[m]);
#pragma unroll
    for (int n = 0; n < 4; ++n) bf[n] = *reinterpret_cast<const s16x8*>(Bb + bofs[n]);

#pragma unroll
    for (int m = 0; m < 8; ++m)
#pragma unroll
      for (int n = 0; n < 4; ++n)
        acc[m][n] = __builtin_amdgcn_mfma_f32_16x16x32_bf16(af[m], bf[n], acc[m][n], 0, 0, 0);

    // All tile-t ds_reads complete before the barrier (closes the LDS
    // overwrite race vs STAGE(t+4) issued after the barrier), regardless
    // of any MFMA sinking. Near-free: reads were already consumed.
    LGKMCNT0();
    __builtin_amdgcn_sched_barrier(0);
    // tile t+1 must be landed: only tiles t+2,t+3 (8 loads) may stay in flight
    if (t < NT - 3)       { VMCNT(8); }
    else if (t == NT - 3) { VMCNT(4); }
    else                  { VMCNT(0); }
    BARRIER();
  }

#undef STAGE_A
#undef STAGE_B

  // Epilogue: C/D layout col = lane&15, row = (lane>>4)*4 + j
  const int crow0 = bm * BM + wr * 128 + (lane >> 4) * 4;
  const int ccol0 = bn * BN + wc * 64 + (lane & 15);
#pragma unroll
  for (int m = 0; m < 8; ++m)
#pragma unroll
    for (int n = 0; n < 4; ++n)
#pragma unroll
      for (int j = 0; j < 4; ++j) {
        const float v = acc[m][n][j];
        C[(size_t)(crow0 + m * 16 + j) * DOUT + (ccol0 + n * 16)] = 1.f / (1.f + __expf(-v));
      }
}

extern "C" void kernel_launch(void* const* d_in, const int* in_sizes, int n_in,
                              void* d_out, int out_size, void* d_ws, size_t ws_size,
                              hipStream_t stream) {
  const float* x = (const float*)d_in[0];
  const float* W = (const float*)d_in[1];
  float* out = (float*)d_out;

  // workspace: xn bf16 [8192,4096] (64 MiB) | Wb bf16 [16384,4096] (128 MiB)
  unsigned short* xn = (unsigned short*)d_ws;
  unsigned short* Wb = xn + (size_t)TOKENS * DIN;

  ln_kernel<<<TOKENS, 256, 0, stream>>>(x, xn);
  cvt_kernel<<<((size_t)DOUT * DIN) / 1024, 256, 0, stream>>>(W, Wb);
  gemm_sig<<<(TOKENS / BM) * (DOUT / BN), 512, 0, stream>>>(xn, Wb, out);
}

// Round 4
// 1340.823 us; speedup vs baseline: 1.6269x; 1.3055x over previous
//
#include <hip/hip_runtime.h>
#include <hip/hip_bf16.h>
#include <stdint.h>

#define TOKENS 8192
#define DIN    4096
#define DOUT   16384

#define BM 256
#define BN 256
#define BKT 64                 // K per tile
#define NT (DIN / BKT)         // 64 K-tiles
#define NJ (NT / 2)            // 32 iterations, 2 tiles each

typedef short s16x8 __attribute__((ext_vector_type(8)));
typedef float f32x4 __attribute__((ext_vector_type(4)));

#define AS1 __attribute__((address_space(1)))
#define AS3 __attribute__((address_space(3)))
#define VMCNT(n)  asm volatile("s_waitcnt vmcnt(" #n ")" ::: "memory")
#define LGKM0()   asm volatile("s_waitcnt lgkmcnt(0)" ::: "memory")
#define SCHEDB()  __builtin_amdgcn_sched_barrier(0)
#define BAR()     __builtin_amdgcn_s_barrier()

__device__ __forceinline__ unsigned short f2bf(float f) {
  unsigned int u = __float_as_uint(f);
  u += 0x7fffu + ((u >> 16) & 1u);   // round-to-nearest-even
  return (unsigned short)(u >> 16);
}

// -------- Kernel 1: LayerNorm fp32 -> bf16
__global__ __launch_bounds__(256) void ln_kernel(const float* __restrict__ x,
                                                 unsigned short* __restrict__ xn) {
  const int row = blockIdx.x;
  const float4* xr = reinterpret_cast<const float4*>(x + (size_t)row * DIN);
  float4 v[4];
  float sum = 0.f, ssq = 0.f;
#pragma unroll
  for (int i = 0; i < 4; ++i) {
    v[i] = xr[threadIdx.x + i * 256];
    sum += v[i].x + v[i].y + v[i].z + v[i].w;
    ssq += v[i].x * v[i].x + v[i].y * v[i].y + v[i].z * v[i].z + v[i].w * v[i].w;
  }
#pragma unroll
  for (int off = 32; off > 0; off >>= 1) {
    sum += __shfl_xor(sum, off, 64);
    ssq += __shfl_xor(ssq, off, 64);
  }
  __shared__ float red[8];
  const int wid = threadIdx.x >> 6;
  if ((threadIdx.x & 63) == 0) { red[wid] = sum; red[wid + 4] = ssq; }
  __syncthreads();
  sum = red[0] + red[1] + red[2] + red[3];
  ssq = red[4] + red[5] + red[6] + red[7];
  const float mean = sum * (1.f / DIN);
  const float var  = ssq * (1.f / DIN) - mean * mean;
  const float rs   = rsqrtf(var + 1e-5f);
  ushort4* xo = reinterpret_cast<ushort4*>(xn + (size_t)row * DIN);
#pragma unroll
  for (int i = 0; i < 4; ++i) {
    ushort4 o;
    o.x = f2bf((v[i].x - mean) * rs);
    o.y = f2bf((v[i].y - mean) * rs);
    o.z = f2bf((v[i].z - mean) * rs);
    o.w = f2bf((v[i].w - mean) * rs);
    xo[threadIdx.x + i * 256] = o;
  }
}

// -------- Kernel 2: W fp32 -> bf16
__global__ __launch_bounds__(256) void cvt_kernel(const float* __restrict__ W,
                                                  unsigned short* __restrict__ Wb) {
  const size_t i = (size_t)blockIdx.x * 256 + threadIdx.x;
  float4 v = reinterpret_cast<const float4*>(W)[i];
  ushort4 o;
  o.x = f2bf(v.x); o.y = f2bf(v.y); o.z = f2bf(v.z); o.w = f2bf(v.w);
  reinterpret_cast<ushort4*>(Wb)[i] = o;
}

// -------- Kernel 3: C = sigmoid(A @ B^T), 8-phase 256x256 schedule.
// 8 waves (2x4), wave tile 128x64, BK=64, dbuf LDS (128 KiB).
// Per iter: tiles t0=2j (buf0), t1=2j+1 (buf1); 8 phases = 4 quadrants x 2.
// Stage slots: ph1,2 -> A[1] halves (tile t1); ph3,4 -> B[0] (t2);
// ph5,6 -> A[0] (t2); ph7,8 -> B[1] (t3).  vmcnt(4) at ph4 & ph8 only.
// Hazard proof: every region staged >=1 closing-barrier after its last read;
// every region landed (vmcnt checkpoint) before its first read.
__global__ __launch_bounds__(512, 2) void gemm_sig(const unsigned short* __restrict__ A,
                                                   const unsigned short* __restrict__ B,
                                                   float* __restrict__ C) {
  __shared__ unsigned short Asl[2 * 256 * 64];  // 64 KB: [p][row 0..255][slot*8]
  __shared__ unsigned short Bsl[2 * 256 * 64];  // 64 KB

  const int bid = blockIdx.x;
  const int cpx = gridDim.x >> 3;
  const int swz = (bid & 7) * cpx + (bid >> 3);
  const int bm = swz & 31;      // TOKENS/BM = 32
  const int bn = swz >> 5;      // DOUT/BN  = 64

  const int tid  = threadIdx.x;
  const int wid  = tid >> 6;
  const int lane = tid & 63;
  const int wr = wid >> 2, wc = wid & 3;

  const unsigned short* gA = A + (size_t)bm * BM * DIN;
  const unsigned short* gB = B + (size_t)bn * BN * DIN;

  // Staging: instr i covers rows i*64..i*64+63 of a 128-row half.
  // Lane l writes LDS (row = i*64+wid*8+(l>>3), slot = l&7) [linear dest];
  // fetches global slot c = (l&7) ^ (l>>3)  (involution swizzle, row&7 key).
  const int l8 = lane >> 3, l7 = lane & 7;
  const int csw = l7 ^ l8;
  const unsigned short* sA0 = gA + (size_t)(wid * 8 + l8) * DIN + csw * 8;
  const unsigned short* sA1 = sA0 + (size_t)64 * DIN;
  const unsigned short* sB0 = gB + (size_t)(wid * 8 + l8) * DIN + csw * 8;
  const unsigned short* sB1 = sB0 + (size_t)64 * DIN;
  const int dOfs = wid * 512;   // ushort units (wave base within 64-row instr span)

#define STG_A(p, h, kt) do { \
  __builtin_amdgcn_global_load_lds((const AS1 void*)(sA0 + (size_t)(h) * 128 * DIN + (kt) * BKT), \
      (AS3 void*)(Asl + ((p) * 256 + (h) * 128) * 64 + dOfs), 16, 0, 0); \
  __builtin_amdgcn_global_load_lds((const AS1 void*)(sA1 + (size_t)(h) * 128 * DIN + (kt) * BKT), \
      (AS3 void*)(Asl + ((p) * 256 + (h) * 128 + 64) * 64 + dOfs), 16, 0, 0); } while (0)
#define STG_B(p, h, kt) do { \
  __builtin_amdgcn_global_load_lds((const AS1 void*)(sB0 + (size_t)(h) * 128 * DIN + (kt) * BKT), \
      (AS3 void*)(Bsl + ((p) * 256 + (h) * 128) * 64 + dOfs), 16, 0, 0); \
  __builtin_amdgcn_global_load_lds((const AS1 void*)(sB1 + (size_t)(h) * 128 * DIN + (kt) * BKT), \
      (AS3 void*)(Bsl + ((p) * 256 + (h) * 128 + 64) * 64 + dOfs), 16, 0, 0); } while (0)

  // Read side: frag row r, logical k-slot q=(lane>>4)+4*kh stored at slot q^(r&7);
  // r&7 == lane&7 (all row bases are multiples of 8) -> lane-only offsets.
  const int aBase = (wr * 128 + (lane & 15)) * 64;
  const int bBase = (wc * 64 + (lane & 15)) * 64;
  const int slt0 = (((lane >> 4)) ^ l7) * 8;
  const int slt1 = (((lane >> 4) + 4) ^ l7) * 8;

  s16x8 af[4][2], bf[4][2];
  f32x4 acc[8][4] = {};

#define LDA(p, MB) do { _Pragma("unroll") for (int mm = 0; mm < 4; ++mm) { \
    const unsigned short* _b = Asl + (p) * 16384 + aBase + ((MB) + mm) * 1024; \
    af[mm][0] = *reinterpret_cast<const s16x8*>(_b + slt0); \
    af[mm][1] = *reinterpret_cast<const s16x8*>(_b + slt1); } } while (0)
#define LDB(p, NB) do { _Pragma("unroll") for (int nn = 0; nn < 2; ++nn) { \
    const unsigned short* _b = Bsl + (p) * 16384 + bBase + ((NB) + nn) * 1024; \
    bf[(NB) + nn][0] = *reinterpret_cast<const s16x8*>(_b + slt0); \
    bf[(NB) + nn][1] = *reinterpret_cast<const s16x8*>(_b + slt1); } } while (0)

#define QUAD(MB, NB) do { _Pragma("unroll") for (int mm = 0; mm < 4; ++mm) { \
    _Pragma("unroll") for (int nn = 0; nn < 2; ++nn) { \
      acc[(MB)+mm][(NB)+nn] = __builtin_amdgcn_mfma_f32_16x16x32_bf16(af[mm][0], bf[(NB)+nn][0], acc[(MB)+mm][(NB)+nn], 0, 0, 0); \
      acc[(MB)+mm][(NB)+nn] = __builtin_amdgcn_mfma_f32_16x16x32_bf16(af[mm][1], bf[(NB)+nn][1], acc[(MB)+mm][(NB)+nn], 0, 0, 0); } } } while (0)

#define PH_TOP()  SCHEDB(); BAR()
#define PH_BOT()  LGKM0(); SCHEDB(); BAR()

  // Prologue: tile0 all 4 regions, tile1 B halves. vmcnt(4) -> tile0 landed.
  STG_B(0, 0, 0); STG_B(0, 1, 0); STG_A(0, 0, 0); STG_A(0, 1, 0);
  STG_B(1, 0, 1); STG_B(1, 1, 1);
  VMCNT(4); SCHEDB(); BAR();

  for (int j = 0; j < NJ - 1; ++j) {
    const int t1 = 2 * j + 1, t2 = 2 * j + 2, t3 = 2 * j + 3;
    // ph1: reads q1(t0) [12], stage A[1][0](t1)
    LDA(0, 0); LDB(0, 0); STG_A(1, 0, t1); PH_TOP();
    __builtin_amdgcn_s_setprio(1); QUAD(0, 0); __builtin_amdgcn_s_setprio(0); PH_BOT();
    // ph2: reads B n2-3 [4], stage A[1][1](t1)
    LDB(0, 2); STG_A(1, 1, t1); PH_TOP();
    __builtin_amdgcn_s_setprio(1); QUAD(0, 2); __builtin_amdgcn_s_setprio(0); PH_BOT();
    // ph3: reads A m4-7 [8], stage B[0][0](t2)
    LDA(0, 4); STG_B(0, 0, t2); PH_TOP();
    __builtin_amdgcn_s_setprio(1); QUAD(4, 0); __builtin_amdgcn_s_setprio(0); PH_BOT();
    // ph4: stage B[0][1](t2), vmcnt checkpoint
    STG_B(0, 1, t2); PH_TOP();
    __builtin_amdgcn_s_setprio(1); QUAD(4, 2); __builtin_amdgcn_s_setprio(0);
    LGKM0(); VMCNT(4); SCHEDB(); BAR();
    // ph5: tile t1 (buf1) q1, stage A[0][0](t2)
    LDA(1, 0); LDB(1, 0); STG_A(0, 0, t2); PH_TOP();
    __builtin_amdgcn_s_setprio(1); QUAD(0, 0); __builtin_amdgcn_s_setprio(0); PH_BOT();
    // ph6: stage A[0][1](t2)
    LDB(1, 2); STG_A(0, 1, t2); PH_TOP();
    __builtin_amdgcn_s_setprio(1); QUAD(0, 2); __builtin_amdgcn_s_setprio(0); PH_BOT();
    // ph7: stage B[1][0](t3)
    LDA(1, 4); STG_B(1, 0, t3); PH_TOP();
    __builtin_amdgcn_s_setprio(1); QUAD(4, 0); __builtin_amdgcn_s_setprio(0); PH_BOT();
    // ph8: stage B[1][1](t3), vmcnt checkpoint
    STG_B(1, 1, t3); PH_TOP();
    __builtin_amdgcn_s_setprio(1); QUAD(4, 2); __builtin_amdgcn_s_setprio(0);
    LGKM0(); VMCNT(4); SCHEDB(); BAR();
  }

  // Tail iter (t0 = NT-2, t1 = NT-1): only A[1](t1) staged; drain at ph4.
  {
    const int t1 = NT - 1;
    LDA(0, 0); LDB(0, 0); STG_A(1, 0, t1); PH_TOP();
    __builtin_amdgcn_s_setprio(1); QUAD(0, 0); __builtin_amdgcn_s_setprio(0); PH_BOT();
    LDB(0, 2); STG_A(1, 1, t1); PH_TOP();
    __builtin_amdgcn_s_setprio(1); QUAD(0, 2); __builtin_amdgcn_s_setprio(0); PH_BOT();
    LDA(0, 4); PH_TOP();
    __builtin_amdgcn_s_setprio(1); QUAD(4, 0); __builtin_amdgcn_s_setprio(0); PH_BOT();
    PH_TOP();
    __builtin_amdgcn_s_setprio(1); QUAD(4, 2); __builtin_amdgcn_s_setprio(0);
    LGKM0(); VMCNT(0); SCHEDB(); BAR();
    LDA(1, 0); LDB(1, 0); PH_TOP();
    __builtin_amdgcn_s_setprio(1); QUAD(0, 0); __builtin_amdgcn_s_setprio(0); PH_BOT();
    LDB(1, 2); PH_TOP();
    __builtin_amdgcn_s_setprio(1); QUAD(0, 2); __builtin_amdgcn_s_setprio(0); PH_BOT();
    LDA(1, 4); PH_TOP();
    __builtin_amdgcn_s_setprio(1); QUAD(4, 0); __builtin_amdgcn_s_setprio(0); PH_BOT();
    __builtin_amdgcn_s_setprio(1); QUAD(4, 2); __builtin_amdgcn_s_setprio(0);
  }

#undef STG_A
#undef STG_B
#undef LDA
#undef LDB
#undef QUAD
#undef PH_TOP
#undef PH_BOT

  // Epilogue: C/D layout col = lane&15, row = (lane>>4)*4 + j
  const int crow0 = bm * BM + wr * 128 + (lane >> 4) * 4;
  const int ccol0 = bn * BN + wc * 64 + (lane & 15);
#pragma unroll
  for (int m = 0; m < 8; ++m)
#pragma unroll
    for (int n = 0; n < 4; ++n)
#pragma unroll
      for (int jj = 0; jj < 4; ++jj) {
        const float v = acc[m][n][jj];
        C[(size_t)(crow0 + m * 16 + jj) * DOUT + (ccol0 + n * 16)] = 1.f / (1.f + __expf(-v));
      }
}

extern "C" void kernel_launch(void* const* d_in, const int* in_sizes, int n_in,
                              void* d_out, int out_size, void* d_ws, size_t ws_size,
                              hipStream_t stream) {
  const float* x = (const float*)d_in[0];
  const float* W = (const float*)d_in[1];
  float* out = (float*)d_out;

  unsigned short* xn = (unsigned short*)d_ws;                    // 64 MiB
  unsigned short* Wb = xn + (size_t)TOKENS * DIN;                // 128 MiB

  ln_kernel<<<TOKENS, 256, 0, stream>>>(x, xn);
  cvt_kernel<<<((size_t)DOUT * DIN) / 1024, 256, 0, stream>>>(W, Wb);
  gemm_sig<<<(TOKENS / BM) * (DOUT / BN), 512, 0, stream>>>(xn, Wb, out);
}